// Round 1
// baseline (5349.517 us; speedup 1.0000x reference)
//
#include <hip/hip_runtime.h>
#include <hip/hip_bf16.h>

#define B_DIM 128
#define T_DIM 256
#define N_DIM 1024
#define TN (T_DIM * N_DIM)
#define BN (B_DIM * N_DIM)
#define PI_OFF ((size_t)B_DIM * TN)   // floats: 33,554,432

#define NWG 128
#define PITCH 1032                    // ushorts per LDS Pi column (1024 + 8 pad)

// workspace layout (bytes)
#define WS_IHI 0
#define WS_ILO (WS_IHI + 2 * BN * 2)            // 524,288
#define WS_RMAX (WS_ILO + 2 * BN * 2)           // 1,048,576
#define WS_RSUM (WS_RMAX + 4096)
#define WS_BAR (WS_RSUM + 4096)                 // 1,056,768
#define WS_BAR_BYTES (256 * 128)

#define SMEM_BYTES (32 * PITCH * 2 * 2 + 3 * 64 * 16 * 4)  // 144,384

using bf16x8 = __attribute__((ext_vector_type(8))) short;
using f32x16 = __attribute__((ext_vector_type(16))) float;

__device__ __forceinline__ unsigned short f2bf(float x) {
  union { float f; unsigned u; } c; c.f = x;
  unsigned r = c.u + 0x7FFFu + ((c.u >> 16) & 1u);   // RNE
  return (unsigned short)(r >> 16);
}
__device__ __forceinline__ float bf2f(unsigned short h) {
  union { unsigned u; float f; } c; c.u = ((unsigned)h) << 16;
  return c.f;
}

// ---------------- setup kernels ----------------

__global__ void __launch_bounds__(256) rowstats_kernel(const float* __restrict__ logits,
                                                       float* __restrict__ rmax,
                                                       float* __restrict__ rsum) {
  const int lane = threadIdx.x & 63;
  const int wv = threadIdx.x >> 6;
  const int row = blockIdx.x * 4 + wv;
  const float4* pr = (const float4*)(logits + (size_t)row * N_DIM);
  float4 v[4];
#pragma unroll
  for (int j = 0; j < 4; ++j) v[j] = pr[lane * 4 + j];
  float m = -1e30f;
#pragma unroll
  for (int j = 0; j < 4; ++j)
    m = fmaxf(m, fmaxf(fmaxf(v[j].x, v[j].y), fmaxf(v[j].z, v[j].w)));
#pragma unroll
  for (int off = 32; off > 0; off >>= 1) m = fmaxf(m, __shfl_xor(m, off, 64));
  float sum = 0.f;
#pragma unroll
  for (int j = 0; j < 4; ++j)
    sum += expf(v[j].x - m) + expf(v[j].y - m) + expf(v[j].z - m) + expf(v[j].w - m);
#pragma unroll
  for (int off = 32; off > 0; off >>= 1) sum += __shfl_xor(sum, off, 64);
  if (lane == 0) { rmax[row] = m; rsum[row] = sum; }
}

__global__ void __launch_bounds__(256) pi_kernel(const float* __restrict__ logits,
                                                 const float* __restrict__ rmax,
                                                 const float* __restrict__ rsum,
                                                 float* __restrict__ pi_out) {
  const int row = blockIdx.x;
  const float m = rmax[row];
  const float rs = 1.0f / rsum[row];
  const float4* src = (const float4*)(logits + (size_t)row * N_DIM);
  float4* dst = (float4*)(pi_out + (size_t)row * N_DIM);
  float4 v = src[threadIdx.x];
  float4 o;
  o.x = expf(v.x - m) * rs;
  o.y = expf(v.y - m) * rs;
  o.z = expf(v.z - m) * rs;
  o.w = expf(v.w - m) * rs;
  dst[threadIdx.x] = o;
}

__global__ void __launch_bounds__(256) init_kernel(const float* __restrict__ x_hist,
                                                   float* __restrict__ out,
                                                   unsigned short* __restrict__ ihi,
                                                   unsigned short* __restrict__ ilo) {
  const int idx = blockIdx.x * 256 + threadIdx.x;   // 0..131071
  const int b = idx >> 10;
  const int n = idx & 1023;
  float v = fmaxf(x_hist[(size_t)b * TN + n], 0.0f);
  out[(size_t)b * TN + n] = v;   // I_sim[:,0,:]
  unsigned short h = f2bf(v);
  ihi[idx] = h;
  ilo[idx] = f2bf(v - bf2f(h));
}

// ---------------- grid barrier (2-level tree, agent scope) ----------------

__device__ __forceinline__ void grid_barrier(int* bar, int slot) {
  __syncthreads();
  if (threadIdx.x == 0) {
    int* base = bar + slot * 32;  // [0..7]=leaf, [8]=root, [16]=gen (separate 64B line)
    __threadfence();
    const int leaf = (int)(blockIdx.x >> 4);    // 8 leaves x 16 WGs
    int p = __hip_atomic_fetch_add(base + leaf, 1, __ATOMIC_ACQ_REL, __HIP_MEMORY_SCOPE_AGENT);
    if (p == 15) {
      int q = __hip_atomic_fetch_add(base + 8, 1, __ATOMIC_ACQ_REL, __HIP_MEMORY_SCOPE_AGENT);
      if (q == 7) {
        __hip_atomic_store(base + 16, 1, __ATOMIC_RELEASE, __HIP_MEMORY_SCOPE_AGENT);
      }
    }
    while (__hip_atomic_load(base + 16, __ATOMIC_ACQUIRE, __HIP_MEMORY_SCOPE_AGENT) == 0) {
      __builtin_amdgcn_s_sleep(1);
    }
    __threadfence();
  }
  __syncthreads();
}

// ---------------- main persistent kernel ----------------

__global__ void __launch_bounds__(256, 1)
seir_main(const float* __restrict__ beta,
          const float* __restrict__ sigma,
          const float* __restrict__ gamma,
          float* __restrict__ out,          // d_out base (I_sim, then Pi at PI_OFF)
          unsigned short* __restrict__ ihi, // [2][128][1024]
          unsigned short* __restrict__ ilo,
          int* __restrict__ bar) {
  extern __shared__ char smem_raw[];
  unsigned short* pih = (unsigned short*)smem_raw;       // [32][PITCH]
  unsigned short* pil = pih + 32 * PITCH;
  float* red = (float*)(pil + 32 * PITCH);               // [3][64][16]

  const int tid = threadIdx.x;
  const int lane = tid & 63;
  const int wv = tid >> 6;          // 0..3, K-split quarter
  const int cb = (int)blockIdx.x & 31;
  const int rb = (int)blockIdx.x >> 5;

  const float* pi_f32 = out + PI_OFF;

  // stage Pi slice (cols cb*32..+32) into LDS as transposed bf16 hi/lo
  {
    const int tx = tid & 31;
    const int ty = tid >> 5;
    const float* src = pi_f32 + (size_t)(cb * 32 + tx);
    unsigned short* dh = pih + tx * PITCH;
    unsigned short* dl = pil + tx * PITCH;
    for (int k = ty; k < N_DIM; k += 8) {
      float p = src[(size_t)k * N_DIM];
      unsigned short h = f2bf(p);
      dh[k] = h;
      dl[k] = f2bf(p - bf2f(h));
    }
  }
  __syncthreads();

  const int colg = cb * 32 + (lane & 31);   // n index
  const int kq = wv * 256;                  // wave's K quarter
  const int kg = (lane >> 5) * 8;           // k-group within K=16 step
  const int arow = rb * 32 + (lane & 31);   // b index for A rows

  // wave-0 register-resident state
  float S[16], E[16], Iv[16];
  float bet = 0.f, sig = 0.f, gam = 0.f;
  if (wv == 0) {
    bet = beta[colg]; sig = sigma[colg]; gam = gamma[colg];
#pragma unroll
    for (int r = 0; r < 16; ++r) {
      int rg = rb * 32 + ((r & 3) + 8 * (r >> 2) + 4 * (lane >> 5));
      S[r] = 0.99f;
      E[r] = 0.0f;
      Iv[r] = out[(size_t)rg * TN + colg];   // t=0 slice
    }
  }

  const unsigned short* pBh = pih + (lane & 31) * PITCH + kq + kg;
  const unsigned short* pBl = pil + (lane & 31) * PITCH + kq + kg;
  const size_t aofs = (size_t)arow * N_DIM + kq + kg;

  for (int t = 1; t < T_DIM; ++t) {
    const unsigned short* Ah = ihi + (size_t)((t - 1) & 1) * BN + aofs;
    const unsigned short* Al = ilo + (size_t)((t - 1) & 1) * BN + aofs;

    f32x16 aHH = {};
    f32x16 aLH = {};
    f32x16 aHL = {};
#pragma unroll
    for (int kk = 0; kk < 16; ++kk) {
      bf16x8 ah = *(const bf16x8*)(Ah + kk * 16);
      bf16x8 al = *(const bf16x8*)(Al + kk * 16);
      bf16x8 bh = *(const bf16x8*)(pBh + kk * 16);
      bf16x8 bl = *(const bf16x8*)(pBl + kk * 16);
      aHH = __builtin_amdgcn_mfma_f32_32x32x16_bf16(ah, bh, aHH, 0, 0, 0);
      aLH = __builtin_amdgcn_mfma_f32_32x32x16_bf16(al, bh, aLH, 0, 0, 0);
      aHL = __builtin_amdgcn_mfma_f32_32x32x16_bf16(ah, bl, aHL, 0, 0, 0);
    }

    f32x16 s = aHH + aLH + aHL;
    if (wv != 0) {
      float* dst = red + ((wv - 1) * 64 + lane) * 16;
#pragma unroll
      for (int r = 0; r < 16; ++r) dst[r] = s[r];
    }
    __syncthreads();
    if (wv == 0) {
#pragma unroll
      for (int w = 0; w < 3; ++w) {
        const float* sp = red + (w * 64 + lane) * 16;
#pragma unroll
        for (int r = 0; r < 16; ++r) s[r] += sp[r];
      }
      unsigned short* oh = ihi + (size_t)(t & 1) * BN;
      unsigned short* ol = ilo + (size_t)(t & 1) * BN;
#pragma unroll
      for (int r = 0; r < 16; ++r) {
        int rg = rb * 32 + ((r & 3) + 8 * (r >> 2) + 4 * (lane >> 5));
        float lam = s[r];
        float En = E[r] + bet * S[r] * lam - sig * E[r];
        float In = fmaxf(Iv[r] + sig * E[r] - gam * Iv[r], 0.0f);
        float Sn = fmaxf(1.0f - (En + In), 0.01f);
        E[r] = En; Iv[r] = In; S[r] = Sn;
        out[(size_t)rg * TN + (size_t)t * N_DIM + colg] = In;
        unsigned short h = f2bf(In);
        size_t io = (size_t)rg * N_DIM + colg;
        oh[io] = h;
        ol[io] = f2bf(In - bf2f(h));
      }
    }
    if (t < T_DIM - 1) grid_barrier(bar, t - 1);
  }
}

// ---------------- launcher ----------------

extern "C" void kernel_launch(void* const* d_in, const int* in_sizes, int n_in,
                              void* d_out, int out_size, void* d_ws, size_t ws_size,
                              hipStream_t stream) {
  const float* x_hist = (const float*)d_in[0];
  const float* beta = (const float*)d_in[1];
  const float* sigma = (const float*)d_in[2];
  const float* gamma = (const float*)d_in[3];
  const float* pi_logits = (const float*)d_in[4];
  float* out = (float*)d_out;
  char* ws = (char*)d_ws;
  unsigned short* ihi = (unsigned short*)(ws + WS_IHI);
  unsigned short* ilo = (unsigned short*)(ws + WS_ILO);
  float* rmax = (float*)(ws + WS_RMAX);
  float* rsum = (float*)(ws + WS_RSUM);
  int* bar = (int*)(ws + WS_BAR);

  (void)in_sizes; (void)n_in; (void)out_size; (void)ws_size;

  hipFuncSetAttribute((const void*)seir_main,
                      hipFuncAttributeMaxDynamicSharedMemorySize, SMEM_BYTES);

  rowstats_kernel<<<256, 256, 0, stream>>>(pi_logits, rmax, rsum);
  pi_kernel<<<1024, 256, 0, stream>>>(pi_logits, rmax, rsum, out + PI_OFF);
  init_kernel<<<512, 256, 0, stream>>>(x_hist, out, ihi, ilo);
  hipMemsetAsync(bar, 0, WS_BAR_BYTES, stream);
  seir_main<<<NWG, 256, SMEM_BYTES, stream>>>(beta, sigma, gamma, out, ihi, ilo, bar);
}

// Round 9
// 3372.132 us; speedup vs baseline: 1.5864x; 1.5864x over previous
//
#include <hip/hip_runtime.h>
#include <hip/hip_bf16.h>

#define B_DIM 128
#define T_DIM 256
#define N_DIM 1024
#define TN (T_DIM * N_DIM)
#define BN (B_DIM * N_DIM)
#define PI_OFF ((size_t)B_DIM * TN)   // floats

#define PITCH 1032                    // u16 per LDS Pi column (1024 + 8)

// workspace layout (bytes)
#define WS_IHI 0
#define WS_ILO (2 * BN * 2)                     // 524288
#define WS_BAR (WS_ILO + 2 * BN * 2)            // 1048576
#define WS_BAR_BYTES (T_DIM * 4 * 32 * 4)       // 131072
#define WS_RMAX (WS_BAR + WS_BAR_BYTES)
#define WS_RSUM (WS_RMAX + 4096)

#define SMEM_BYTES (2 * 32 * PITCH * 2 + 32 * 36 * 4)  // 136704

using bf16x8 = __attribute__((ext_vector_type(8))) short;
using f32x16 = __attribute__((ext_vector_type(16))) float;
using f32x4  = __attribute__((ext_vector_type(4))) float;
using u32x4  = __attribute__((ext_vector_type(4))) unsigned int;

__device__ __forceinline__ unsigned short f2bf(float x) {
  union { float f; unsigned u; } c; c.f = x;
  unsigned r = c.u + 0x7FFFu + ((c.u >> 16) & 1u);   // RNE
  return (unsigned short)(r >> 16);
}
__device__ __forceinline__ float bf2f(unsigned short h) {
  union { unsigned u; float f; } c; c.u = ((unsigned)h) << 16;
  return c.f;
}
__device__ __forceinline__ bf16x8 as_bf16x8(u32x4 v) {
  union { u32x4 u; bf16x8 b; } c; c.u = v; return c.b;
}

// Consumer loads: sc0 sc1 bypass L0+L2, read straight from MALL (proven
// fresh in r7). Producer stores are NORMAL cached; the release fence's
// buffer_wbl2 pushes them to MALL *with completion* before the flag —
// removes any reliance on vmcnt retirement semantics for bypass stores.
#define GLD(dst, addr) \
  asm volatile("global_load_dwordx4 %0, %1, off sc0 sc1" : "=v"(dst) : "v"(addr))
#define WAITVM(n) do { asm volatile("s_waitcnt vmcnt(" #n ")" ::: "memory"); \
                       __builtin_amdgcn_sched_barrier(0); } while (0)

// ---------------- setup kernels ----------------

__global__ void __launch_bounds__(256) rowstats_kernel(const float* __restrict__ logits,
                                                       float* __restrict__ rmax,
                                                       float* __restrict__ rsum) {
  const int lane = threadIdx.x & 63;
  const int wv = threadIdx.x >> 6;
  const int row = blockIdx.x * 4 + wv;
  const float4* pr = (const float4*)(logits + (size_t)row * N_DIM);
  float4 v[4];
#pragma unroll
  for (int j = 0; j < 4; ++j) v[j] = pr[lane * 4 + j];
  float m = -1e30f;
#pragma unroll
  for (int j = 0; j < 4; ++j)
    m = fmaxf(m, fmaxf(fmaxf(v[j].x, v[j].y), fmaxf(v[j].z, v[j].w)));
#pragma unroll
  for (int off = 32; off > 0; off >>= 1) m = fmaxf(m, __shfl_xor(m, off, 64));
  float sum = 0.f;
#pragma unroll
  for (int j = 0; j < 4; ++j)
    sum += expf(v[j].x - m) + expf(v[j].y - m) + expf(v[j].z - m) + expf(v[j].w - m);
#pragma unroll
  for (int off = 32; off > 0; off >>= 1) sum += __shfl_xor(sum, off, 64);
  if (lane == 0) { rmax[row] = m; rsum[row] = sum; }
}

__global__ void __launch_bounds__(256) pi_kernel(const float* __restrict__ logits,
                                                 const float* __restrict__ rmax,
                                                 const float* __restrict__ rsum,
                                                 float* __restrict__ pi_out) {
  const int row = blockIdx.x;
  const float m = rmax[row];
  const float rs = 1.0f / rsum[row];
  const float4* src = (const float4*)(logits + (size_t)row * N_DIM);
  float4* dst = (float4*)(pi_out + (size_t)row * N_DIM);
  float4 v = src[threadIdx.x];
  float4 o;
  o.x = expf(v.x - m) * rs;
  o.y = expf(v.y - m) * rs;
  o.z = expf(v.z - m) * rs;
  o.w = expf(v.w - m) * rs;
  dst[threadIdx.x] = o;
}

__global__ void __launch_bounds__(256) init_kernel(const float* __restrict__ x_hist,
                                                   float* __restrict__ out,
                                                   unsigned short* __restrict__ ihi,
                                                   unsigned short* __restrict__ ilo) {
  const int idx = blockIdx.x * 256 + threadIdx.x;   // 0..131071
  const int b = idx >> 10;
  const int n = idx & 1023;
  float v = fmaxf(x_hist[(size_t)b * TN + n], 0.0f);
  out[(size_t)b * TN + n] = v;   // I_sim[:,0,:]
  unsigned short h = f2bf(v);
  ihi[idx] = h;
  ilo[idx] = f2bf(v - bf2f(h));
}

// ---------------- main persistent kernel ----------------
// 128 WGs x 64 threads: rb = row-group (32 batch rows), cb = 32-column slice.
// Each WG = ONE wave: full K per step, no intra-WG sync in the loop.

__global__ void __launch_bounds__(64, 1)
seir_main(const float* __restrict__ beta,
          const float* __restrict__ sigma,
          const float* __restrict__ gamma,
          float* __restrict__ out,
          unsigned short* __restrict__ ihi,   // [2][128][1024]
          unsigned short* __restrict__ ilo,
          int* __restrict__ bar) {
  extern __shared__ char smem_raw[];
  unsigned short* pih = (unsigned short*)smem_raw;       // [32][PITCH]
  unsigned short* pil = pih + 32 * PITCH;
  unsigned int* tile = (unsigned int*)(pil + 32 * PITCH); // [32][36] packed C

  const int lane = threadIdx.x;      // 0..63, single wave
  const int cb = (int)blockIdx.x & 31;
  const int rb = (int)blockIdx.x >> 5;

  const float* pi_f32 = out + PI_OFF;

  // ---- stage Pi slice (transposed, bf16 hi/lo) — coalesced row reads ----
  {
    const int tx = lane & 31, ty = lane >> 5;
    const float* src = pi_f32 + (size_t)(cb * 32 + tx);
    unsigned short* dh = pih + tx * PITCH;
    unsigned short* dl = pil + tx * PITCH;
#pragma unroll 4
    for (int it = 0; it < 512; ++it) {
      int k = it * 2 + ty;
      float p = src[(size_t)k * N_DIM];
      unsigned short h = f2bf(p);
      dh[k] = h;
      dl[k] = f2bf(p - bf2f(h));
    }
  }
  __syncthreads();

  const int half = lane >> 5;
  const int trow = lane & 31;
  const int colg = cb * 32 + trow;
  const float bet = beta[colg], sig = sigma[colg], gam = gamma[colg];

  // register-resident per-column state (C-fragment layout)
  float S[16], E[16], Iv[16];
#pragma unroll
  for (int r = 0; r < 16; ++r) {
    int rg = rb * 32 + ((r & 3) + 8 * (r >> 2) + 4 * half);
    S[r] = 0.99f; E[r] = 0.0f;
    Iv[r] = out[(size_t)rg * TN + colg];   // t=0 slice
  }

  const int arow = rb * 32 + trow;      // A row (= also this lane's writeback row)
  const int khalf = half * 8;
  const unsigned short* aH0 = ihi + (size_t)arow * N_DIM + khalf;
  const unsigned short* aL0 = ilo + (size_t)arow * N_DIM + khalf;
  const unsigned short* pBh = pih + trow * PITCH + khalf;
  const unsigned short* pBl = pil + trow * PITCH + khalf;
  const int coff = cb * 32 + half * 16; // writeback col offset within row

#define LOADB(hx, lx, blk) \
    _Pragma("unroll") \
    for (int j = 0; j < 8; ++j) { \
      GLD(hx[j], (const void*)(Ah + ((blk) * 8 + j) * 16)); \
      GLD(lx[j], (const void*)(Al + ((blk) * 8 + j) * 16)); \
    }

#define COMPB(hx, lx, blk) \
    _Pragma("unroll") \
    for (int j = 0; j < 8; ++j) { \
      const int kk = (blk) * 8 + j; \
      bf16x8 bh = *(const bf16x8*)(pBh + kk * 16); \
      bf16x8 bl = *(const bf16x8*)(pBl + kk * 16); \
      bf16x8 ah = as_bf16x8(hx[j]); \
      bf16x8 al = as_bf16x8(lx[j]); \
      aHH = __builtin_amdgcn_mfma_f32_32x32x16_bf16(ah, bh, aHH, 0, 0, 0); \
      aLH = __builtin_amdgcn_mfma_f32_32x32x16_bf16(al, bh, aLH, 0, 0, 0); \
      aHL = __builtin_amdgcn_mfma_f32_32x32x16_bf16(ah, bl, aHL, 0, 0, 0); \
    }

  for (int t = 1; t < T_DIM; ++t) {
    const unsigned short* Ah = aH0 + (size_t)((t - 1) & 1) * BN;
    const unsigned short* Al = aL0 + (size_t)((t - 1) & 1) * BN;

    f32x16 aHH = {}, aLH = {}, aHL = {};
    u32x4 hA[8], lA[8], hB[8], lB[8];

    // 2-deep pipelined K loop: 8 blocks x 8 kk, bypass loads from MALL
    LOADB(hA, lA, 0)
    LOADB(hB, lB, 1)
    WAITVM(16); COMPB(hA, lA, 0) LOADB(hA, lA, 2)
    WAITVM(16); COMPB(hB, lB, 1) LOADB(hB, lB, 3)
    WAITVM(16); COMPB(hA, lA, 2) LOADB(hA, lA, 4)
    WAITVM(16); COMPB(hB, lB, 3) LOADB(hB, lB, 5)
    WAITVM(16); COMPB(hA, lA, 4) LOADB(hA, lA, 6)
    WAITVM(16); COMPB(hB, lB, 5) LOADB(hB, lB, 7)
    WAITVM(16); COMPB(hA, lA, 6)
    WAITVM(0);  COMPB(hB, lB, 7)

    // ---- state update, pack (hi<<16|lo) into LDS transpose tile ----
#pragma unroll
    for (int r = 0; r < 16; ++r) {
      float lam = aHH[r] + aLH[r] + aHL[r];
      float En = E[r] + bet * S[r] * lam - sig * E[r];
      float In = fmaxf(Iv[r] + sig * E[r] - gam * Iv[r], 0.0f);
      float Sn = fmaxf(1.0f - (En + In), 0.01f);
      E[r] = En; Iv[r] = In; S[r] = Sn;
      unsigned short h = f2bf(In);
      unsigned short l = f2bf(In - bf2f(h));
      int row = (r & 3) + 8 * (r >> 2) + 4 * half;
      tile[row * 36 + trow] = ((unsigned)h << 16) | (unsigned)l;
    }
    asm volatile("s_waitcnt lgkmcnt(0)" ::: "memory");
    __builtin_amdgcn_sched_barrier(0);

    // ---- read back transposed: lane -> row trow, 16 cols ----
    u32x4 qs[4];
#pragma unroll
    for (int j = 0; j < 4; ++j)
      qs[j] = *(const u32x4*)(tile + trow * 36 + half * 16 + j * 4);

    u32x4 Hv[2], Lv[2];
#pragma unroll
    for (int j = 0; j < 4; ++j) {
      Hv[j >> 1][(j & 1) * 2 + 0] = __builtin_amdgcn_perm(qs[j][1], qs[j][0], 0x07060302);
      Hv[j >> 1][(j & 1) * 2 + 1] = __builtin_amdgcn_perm(qs[j][3], qs[j][2], 0x07060302);
      Lv[j >> 1][(j & 1) * 2 + 0] = __builtin_amdgcn_perm(qs[j][1], qs[j][0], 0x05040100);
      Lv[j >> 1][(j & 1) * 2 + 1] = __builtin_amdgcn_perm(qs[j][3], qs[j][2], 0x05040100);
    }

    // normal cached stores — pushed to MALL by the release fence below
    const size_t wbuf = (size_t)(t & 1) * BN;
    unsigned short* dH = ihi + wbuf + (size_t)arow * N_DIM + coff;
    unsigned short* dL = ilo + wbuf + (size_t)arow * N_DIM + coff;
    *reinterpret_cast<u32x4*>(dH) = Hv[0];
    *reinterpret_cast<u32x4*>(dH + 8) = Hv[1];
    *reinterpret_cast<u32x4*>(dL) = Lv[0];
    *reinterpret_cast<u32x4*>(dL + 8) = Lv[1];

    float* dO = out + (size_t)arow * TN + (size_t)t * N_DIM + coff;
#pragma unroll
    for (int j = 0; j < 4; ++j) {
      f32x4 o;
#pragma unroll
      for (int e = 0; e < 4; ++e) {
        unsigned p = qs[j][e];
        o[e] = __uint_as_float(p & 0xFFFF0000u) + __uint_as_float(p << 16);
      }
      *(f32x4*)(dO + j * 4) = o;
    }

    // ---- per-row-group barrier (32 WGs) ----
    // Release: agent fence (s_waitcnt + buffer_wbl2 + wait) — data AT MALL
    // with completion before the flag. Consumers' sc0sc1 loads then read
    // MALL directly; no consumer-side invalidate needed.
    if (t < T_DIM - 1) {
      __builtin_amdgcn_fence(__ATOMIC_RELEASE, "agent");
      int* cl = bar + ((t << 2) + rb) * 32;   // cnt at +0, flag at +16 (64B apart)
      if (lane == 0) {
        int old = __hip_atomic_fetch_add(cl, 1, __ATOMIC_RELAXED, __HIP_MEMORY_SCOPE_AGENT);
        if (old == 31)
          __hip_atomic_store(cl + 16, 1, __ATOMIC_RELAXED, __HIP_MEMORY_SCOPE_AGENT);
      }
      int spins = 0;
      while (__hip_atomic_load(cl + 16, __ATOMIC_RELAXED, __HIP_MEMORY_SCOPE_AGENT) == 0) {
        __builtin_amdgcn_s_sleep(2);
        if (++spins > 50000) break;   // ~15 ms safety valve, never legit
      }
      __builtin_amdgcn_sched_barrier(0);
    }
  }
}

// ---------------- launcher ----------------

extern "C" void kernel_launch(void* const* d_in, const int* in_sizes, int n_in,
                              void* d_out, int out_size, void* d_ws, size_t ws_size,
                              hipStream_t stream) {
  const float* x_hist = (const float*)d_in[0];
  const float* beta = (const float*)d_in[1];
  const float* sigma = (const float*)d_in[2];
  const float* gamma = (const float*)d_in[3];
  const float* pi_logits = (const float*)d_in[4];
  float* out = (float*)d_out;
  char* ws = (char*)d_ws;
  unsigned short* ihi = (unsigned short*)(ws + WS_IHI);
  unsigned short* ilo = (unsigned short*)(ws + WS_ILO);
  int* bar = (int*)(ws + WS_BAR);
  float* rmax = (float*)(ws + WS_RMAX);
  float* rsum = (float*)(ws + WS_RSUM);

  (void)in_sizes; (void)n_in; (void)out_size; (void)ws_size;

  hipFuncSetAttribute((const void*)seir_main,
                      hipFuncAttributeMaxDynamicSharedMemorySize, SMEM_BYTES);

  rowstats_kernel<<<256, 256, 0, stream>>>(pi_logits, rmax, rsum);
  pi_kernel<<<1024, 256, 0, stream>>>(pi_logits, rmax, rsum, out + PI_OFF);
  init_kernel<<<512, 256, 0, stream>>>(x_hist, out, ihi, ilo);
  hipMemsetAsync(bar, 0, WS_BAR_BYTES, stream);
  seir_main<<<128, 64, SMEM_BYTES, stream>>>(beta, sigma, gamma, out, ihi, ilo, bar);
}